// Round 1
// baseline (743.060 us; speedup 1.0000x reference)
//
#include <hip/hip_runtime.h>
#include <hip/hip_bf16.h>
#include <float.h>

// Problem constants
#define Bz   4
#define Nn   384
#define Dd   256
#define Hh   4
#define DHh  64
#define HIDn 64
#define NSQ  (384*384)
#define NEG_MAX (-3.40282346638528859812e+38f)

__device__ __forceinline__ float gelu_f(float x){
  return 0.5f * x * (1.0f + erff(x * 0.70710678118654752f));
}
__device__ __forceinline__ float wsum(float v){
  #pragma unroll
  for (int o = 32; o > 0; o >>= 1) v += __shfl_xor(v, o, 64);
  return v;
}
__device__ __forceinline__ float wmax(float v){
  #pragma unroll
  for (int o = 32; o > 0; o >>= 1) v = fmaxf(v, __shfl_xor(v, o, 64));
  return v;
}

// ---------------------------------------------------------------------------
// Fused pair kernel: cont-MLP -> + embeddings -> LN -> gelu -> bias head
// -> *pair_mask -> write bias (B,H,N,N).
// One wave per 64 consecutive j's of a (b,i) row; lane = pair.
// pr kept per-lane: h1[64] in regs (static idx), pr spilled to LDS column.
// ---------------------------------------------------------------------------
__global__ __launch_bounds__(128) void pair_kernel(
    const float* __restrict__ cont, const int* __restrict__ pm,
    const int* __restrict__ dbk, const int* __restrict__ drk,
    const int* __restrict__ rpk, const int* __restrict__ hdk,
    const int* __restrict__ etk, const int* __restrict__ spk,
    const int* __restrict__ sck, const int* __restrict__ dgk,
    const int* __restrict__ ctk,
    const float* __restrict__ W1, const float* __restrict__ b1,
    const float* __restrict__ W2, const float* __restrict__ b2,
    const float* __restrict__ Ed, const float* __restrict__ Edi,
    const float* __restrict__ Er, const float* __restrict__ Eh,
    const float* __restrict__ Ee, const float* __restrict__ Esp,
    const float* __restrict__ Edg, const float* __restrict__ Ec,
    const float* __restrict__ Es,
    const float* __restrict__ lng, const float* __restrict__ lnb,
    const float* __restrict__ bW, const float* __restrict__ bb,
    float* __restrict__ biasOut)
{
  __shared__ float prb[128 * 65];   // per-thread pr column, pad 65 (2-way banks)
  const int tid  = threadIdx.x;
  const int lane = tid & 63;
  const int wid  = blockIdx.x * 2 + (tid >> 6);   // wave id in [0, 9216)
  const int rowId = wid / 6;                       // b*N + i
  const int jb    = wid - rowId * 6;
  const int b     = rowId / Nn;
  const int i     = rowId - b * Nn;
  const int j     = jb * 64 + lane;
  const size_t p  = (size_t)rowId * Nn + j;

  const int xdb = dbk[p], xdr = drk[p], xrp = rpk[p], xhd = hdk[p];
  const int xet = etk[p], xsp = spk[p], xsc = sck[p];
  const int nb  = b * Nn;
  const int dgj = dgk[nb + j], ctj = ctk[nb + j];
  const int dgi = __builtin_amdgcn_readfirstlane(dgk[rowId]);
  const int cti = __builtin_amdgcn_readfirstlane(ctk[rowId]);

  const float* cp = cont + p * 6;
  const float c0 = cp[0], c1 = cp[1], c2 = cp[2], c3 = cp[3], c4 = cp[4], c5 = cp[5];

  float h1[64];
  #pragma unroll
  for (int kk = 0; kk < 64; ++kk) {
    const float* w = W1 + kk * 6;     // uniform -> scalar loads
    float s = b1[kk] + w[0]*c0 + w[1]*c1 + w[2]*c2 + w[3]*c3 + w[4]*c4 + w[5]*c5;
    h1[kk] = gelu_f(s);
  }

  float sum = 0.f, sq = 0.f;
  for (int l = 0; l < 64; ++l) {
    const float* w2r = W2 + l * 64;   // uniform row -> scalar loads
    float a0 = 0.f, a1 = 0.f, a2 = 0.f, a3 = 0.f;
    #pragma unroll
    for (int kk = 0; kk < 64; kk += 4) {
      a0 = fmaf(w2r[kk+0], h1[kk+0], a0);
      a1 = fmaf(w2r[kk+1], h1[kk+1], a1);
      a2 = fmaf(w2r[kk+2], h1[kk+2], a2);
      a3 = fmaf(w2r[kk+3], h1[kk+3], a3);
    }
    float val = ((a0 + a1) + (a2 + a3)) + b2[l];
    val += Ed [xdb*64 + l] + Edi[xdr*64 + l] + Er[xrp*64 + l] + Eh[xhd*64 + l];
    val += Ee [xet*64 + l] + Esp[xsp*64 + l] + Es[xsc*64 + l];
    val += Edg[dgj*64 + l] + Ec [ctj*64 + l];
    val += Edg[dgi*64 + l] + Ec [cti*64 + l];   // uniform -> scalar
    sum += val; sq = fmaf(val, val, sq);
    prb[tid * 65 + l] = val;
  }

  const float mean = sum * (1.f / 64.f);
  const float var  = sq * (1.f / 64.f) - mean * mean;
  const float inv  = rsqrtf(var + 1e-5f);

  float bh0 = 0.f, bh1 = 0.f, bh2 = 0.f, bh3 = 0.f;
  for (int l = 0; l < 64; ++l) {
    float v = prb[tid * 65 + l];
    float g = gelu_f((v - mean) * inv * lng[l] + lnb[l]);
    bh0 = fmaf(bW[      l], g, bh0);
    bh1 = fmaf(bW[ 64 + l], g, bh1);
    bh2 = fmaf(bW[128 + l], g, bh2);
    bh3 = fmaf(bW[192 + l], g, bh3);
  }
  const float mk = pm[p] ? 1.f : 0.f;
  const size_t base = (size_t)b * (Hh * NSQ) + (size_t)i * Nn + j;
  biasOut[base + 0 * (size_t)NSQ] = (bh0 + bb[0]) * mk;
  biasOut[base + 1 * (size_t)NSQ] = (bh1 + bb[1]) * mk;
  biasOut[base + 2 * (size_t)NSQ] = (bh2 + bb[2]) * mk;
  biasOut[base + 3 * (size_t)NSQ] = (bh3 + bb[3]) * mk;
}

// ---------------------------------------------------------------------------
// LayerNorm over last dim (256). One wave per row, 4 rows per block.
// ---------------------------------------------------------------------------
__global__ __launch_bounds__(256) void ln_kernel(
    const float* __restrict__ x, const float* __restrict__ g,
    const float* __restrict__ bta, float* __restrict__ o)
{
  const int row  = blockIdx.x * 4 + (threadIdx.x >> 6);
  const int lane = threadIdx.x & 63;
  const float4 v = *(const float4*)(x + (size_t)row * Dd + lane * 4);
  float s = v.x + v.y + v.z + v.w;
  s = wsum(s);
  const float m = s * (1.f / 256.f);
  const float dx = v.x - m, dy = v.y - m, dz = v.z - m, dw = v.w - m;
  float q = dx*dx + dy*dy + dz*dz + dw*dw;
  q = wsum(q);
  const float inv = rsqrtf(q * (1.f / 256.f) + 1e-5f);
  const int d = lane * 4;
  const float4 gg = *(const float4*)(g + d);
  const float4 bb = *(const float4*)(bta + d);
  float4 out;
  out.x = dx * inv * gg.x + bb.x;
  out.y = dy * inv * gg.y + bb.y;
  out.z = dz * inv * gg.z + bb.z;
  out.w = dw * inv * gg.w + bb.w;
  *(float4*)(o + (size_t)row * Dd + d) = out;
}

// ---------------------------------------------------------------------------
// Tiled fp32 GEMM, 64x64 tile, TK=16, 4x4 microtile.
// MODE 0: C = A @ B^T (+bias)(+res)          grid (Nc/64, M/64)
// MODE 1: QK^T*scale + biasT, safe-mask      grid (6, 6, B*H)
// MODE 2: C = A @ B  (PV, B natural KxNc)    grid (1, 6, B*H)
// All dims are multiples of tile sizes here -> no bounds checks.
// ---------------------------------------------------------------------------
template<int MODE>
__global__ __launch_bounds__(256) void gemm_kernel(
    const float* __restrict__ A, int sA,
    const float* __restrict__ Bm, int sB,
    float* __restrict__ Cc, int sC,
    const float* __restrict__ bias,
    const float* __restrict__ res, int sR,
    int M, int Nc, int K,
    const float* __restrict__ biasT, const int* __restrict__ pmask,
    const int* __restrict__ valid)
{
  __shared__ float As[16][68];
  __shared__ float Bs[16][68];
  const int tid = threadIdx.x;
  const int tm = tid & 15, tn = tid >> 4;
  const int m0 = blockIdx.y * 64, n0 = blockIdx.x * 64;

  const float* Ab = A; const float* Bb = Bm; float* Cb = Cc;
  const float* biasTb = biasT; const int* pmb = pmask; const int* vlb = valid;
  if (MODE != 0) {
    const int bz = blockIdx.z;
    const int b = bz >> 2, h = bz & 3;
    if (MODE == 1) {
      Ab = A  + (size_t)b * Nn * Dd + h * DHh;
      Bb = Bm + (size_t)b * Nn * Dd + h * DHh;
      Cb = Cc + (size_t)bz * NSQ;
      biasTb = biasT + (size_t)bz * NSQ;
      pmb = pmask + (size_t)b * NSQ;
      vlb = valid + b * Nn;
    } else {
      Ab = A  + (size_t)bz * NSQ;
      Bb = Bm + (size_t)b * Nn * Dd + h * DHh;
      Cb = Cc + (size_t)b * Nn * Dd + h * DHh;
    }
  }

  float acc[4][4] = {};
  for (int k0 = 0; k0 < K; k0 += 16) {
    {
      const int r = tid >> 2, kc = (tid & 3) << 2;
      const float4 v4 = *(const float4*)(Ab + (size_t)(m0 + r) * sA + (k0 + kc));
      As[kc+0][r] = v4.x; As[kc+1][r] = v4.y; As[kc+2][r] = v4.z; As[kc+3][r] = v4.w;
    }
    if (MODE != 2) {
      const int r = tid >> 2, kc = (tid & 3) << 2;
      const float4 v4 = *(const float4*)(Bb + (size_t)(n0 + r) * sB + (k0 + kc));
      Bs[kc+0][r] = v4.x; Bs[kc+1][r] = v4.y; Bs[kc+2][r] = v4.z; Bs[kc+3][r] = v4.w;
    } else {
      const int kk = tid >> 4, nn2 = (tid & 15) << 2;
      *(float4*)&Bs[kk][nn2] = *(const float4*)(Bb + (size_t)(k0 + kk) * sB + (n0 + nn2));
    }
    __syncthreads();
    #pragma unroll
    for (int kk = 0; kk < 16; ++kk) {
      const float4 a4 = *(const float4*)&As[kk][tm << 2];
      const float4 b4 = *(const float4*)&Bs[kk][tn << 2];
      const float av[4] = {a4.x, a4.y, a4.z, a4.w};
      const float bv[4] = {b4.x, b4.y, b4.z, b4.w};
      #pragma unroll
      for (int r = 0; r < 4; ++r)
        #pragma unroll
        for (int s = 0; s < 4; ++s)
          acc[r][s] = fmaf(av[r], bv[s], acc[r][s]);
    }
    __syncthreads();
  }

  #pragma unroll
  for (int r = 0; r < 4; ++r) {
    const int m = m0 + (tm << 2) + r;
    #pragma unroll
    for (int s = 0; s < 4; ++s) {
      const int n = n0 + (tn << 2) + s;
      float v = acc[r][s];
      if (MODE == 0) {
        if (bias) v += bias[n];
        if (res)  v += res[(size_t)m * sR + n];
        Cb[(size_t)m * sC + n] = v;
      } else if (MODE == 1) {
        v = v * 0.125f + biasTb[(size_t)m * Nn + n];
        const bool safe = (pmb[(size_t)m * Nn + n] != 0) || (vlb[m] == 0 && m == n);
        Cb[(size_t)m * Nn + n] = safe ? v : NEG_MAX;
      } else {
        Cb[(size_t)m * sC + n] = v;
      }
    }
  }
}

// ---------------------------------------------------------------------------
// Softmax + pair_mask re-mask + renormalize, in place. Wave per row (384).
// ---------------------------------------------------------------------------
__global__ __launch_bounds__(256) void softmax_kernel(
    float* __restrict__ att, const int* __restrict__ pm)
{
  const int row  = blockIdx.x * 4 + (threadIdx.x >> 6);   // [0, B*H*N)
  const int lane = threadIdx.x & 63;
  const int i  = row % Nn;
  const int bh = row / Nn;
  const int b  = bh / Hh;
  float* ar = att + (size_t)row * Nn;
  const int* pmr = pm + (size_t)b * NSQ + (size_t)i * Nn;

  float v[6];
  float mx = NEG_MAX;
  #pragma unroll
  for (int t = 0; t < 6; ++t) { v[t] = ar[lane + t * 64]; mx = fmaxf(mx, v[t]); }
  mx = wmax(mx);
  float s = 0.f;
  #pragma unroll
  for (int t = 0; t < 6; ++t) { v[t] = expf(v[t] - mx); s += v[t]; }
  s = wsum(s);
  const float invs = 1.f / s;
  float s2 = 0.f;
  #pragma unroll
  for (int t = 0; t < 6; ++t) {
    const float pv = (float)pmr[lane + t * 64];
    v[t] = v[t] * invs * pv;
    s2 += v[t];
  }
  s2 = wsum(s2);
  const float r = 1.f / fmaxf(s2, 1e-6f);
  #pragma unroll
  for (int t = 0; t < 6; ++t) ar[lane + t * 64] = v[t] * r;
}

// ---------------------------------------------------------------------------
// ag = a * gelu(g): h (M,1024) -> ag (M,512)
// ---------------------------------------------------------------------------
__global__ __launch_bounds__(256) void gate_kernel(
    const float* __restrict__ hff, float* __restrict__ ag)
{
  const int idx = blockIdx.x * 256 + threadIdx.x;   // over 1536*512/4
  if (idx >= 1536 * 128) return;
  const int m  = idx / 128;
  const int dq = idx - m * 128;
  const float4 a = *(const float4*)(hff + (size_t)m * 1024 + dq * 4);
  const float4 g = *(const float4*)(hff + (size_t)m * 1024 + 512 + dq * 4);
  float4 o;
  o.x = a.x * gelu_f(g.x); o.y = a.y * gelu_f(g.y);
  o.z = a.z * gelu_f(g.z); o.w = a.w * gelu_f(g.w);
  *(float4*)(ag + (size_t)m * 512 + dq * 4) = o;
}

// ---------------------------------------------------------------------------
extern "C" void kernel_launch(void* const* d_in, const int* in_sizes, int n_in,
                              void* d_out, int out_size, void* d_ws, size_t ws_size,
                              hipStream_t stream) {
  const float* x    = (const float*)d_in[0];
  const int*   pm   = (const int*)  d_in[1];
  const int*   vld  = (const int*)  d_in[2];
  const float* cont = (const float*)d_in[3];
  const int* dbk = (const int*)d_in[4];
  const int* drk = (const int*)d_in[5];
  const int* rpk = (const int*)d_in[6];
  const int* hdk = (const int*)d_in[7];
  const int* etk = (const int*)d_in[8];
  const int* spk = (const int*)d_in[9];
  const int* sck = (const int*)d_in[10];
  const int* dgk = (const int*)d_in[11];
  const int* ctk = (const int*)d_in[12];
  const float* Wq  = (const float*)d_in[13];
  const float* Wk  = (const float*)d_in[14];
  const float* Wv  = (const float*)d_in[15];
  const float* Wo  = (const float*)d_in[16];
  const float* bo  = (const float*)d_in[17];
  const float* cmW1 = (const float*)d_in[18];
  const float* cmb1 = (const float*)d_in[19];
  const float* cmW2 = (const float*)d_in[20];
  const float* cmb2 = (const float*)d_in[21];
  const float* Ed  = (const float*)d_in[22];
  const float* Edi = (const float*)d_in[23];
  const float* Er  = (const float*)d_in[24];
  const float* Eh  = (const float*)d_in[25];
  const float* Ee  = (const float*)d_in[26];
  const float* Esp = (const float*)d_in[27];
  const float* Edg = (const float*)d_in[28];
  const float* Ec  = (const float*)d_in[29];
  const float* Es  = (const float*)d_in[30];
  const float* blng = (const float*)d_in[31];
  const float* blnb = (const float*)d_in[32];
  const float* bW   = (const float*)d_in[33];
  const float* bb_  = (const float*)d_in[34];
  const float* ln1g = (const float*)d_in[35];
  const float* ln1b = (const float*)d_in[36];
  const float* ln2g = (const float*)d_in[37];
  const float* ln2b = (const float*)d_in[38];
  const float* ffW1 = (const float*)d_in[39];
  const float* ffb1 = (const float*)d_in[40];
  const float* ffW2 = (const float*)d_in[41];
  const float* ffb2 = (const float*)d_in[42];

  float* out   = (float*)d_out;
  float* xout  = out;                       // 393216
  float* attn  = out + 393216;              // 2359296 (logits written here, softmaxed in place)
  float* biasO = out + 393216 + 2359296;    // 2359296

  float* ws  = (float*)d_ws;
  float* xn  = ws;                 // 393216  (ln1 out; reused for ln2 out)
  float* qb  = ws + 393216;        // 393216
  float* kb  = ws + 786432;        // 393216
  float* vb  = ws + 1179648;       // 393216
  float* ao  = ws + 1572864;       // 393216
  float* x1  = ws + 1966080;       // 393216
  float* hff = ws + 2359296;       // 1572864  (ends 3932160 floats = 15.7 MB)
  float* ag  = qb;                 // reuse q+k region (dead after QK)

  // 1) pair bias (writes bias output; needed by QK)
  pair_kernel<<<4608, 128, 0, stream>>>(cont, pm, dbk, drk, rpk, hdk, etk, spk,
      sck, dgk, ctk, cmW1, cmb1, cmW2, cmb2, Ed, Edi, Er, Eh, Ee, Esp, Edg, Ec,
      Es, blng, blnb, bW, bb_, biasO);
  // 2) ln1
  ln_kernel<<<384, 256, 0, stream>>>(x, ln1g, ln1b, xn);
  // 3) q, k, v projections
  gemm_kernel<0><<<dim3(4, 24), 256, 0, stream>>>(xn, 256, Wq, 256, qb, 256,
      nullptr, nullptr, 0, 1536, 256, 256, nullptr, nullptr, nullptr);
  gemm_kernel<0><<<dim3(4, 24), 256, 0, stream>>>(xn, 256, Wk, 256, kb, 256,
      nullptr, nullptr, 0, 1536, 256, 256, nullptr, nullptr, nullptr);
  gemm_kernel<0><<<dim3(4, 24), 256, 0, stream>>>(xn, 256, Wv, 256, vb, 256,
      nullptr, nullptr, 0, 1536, 256, 256, nullptr, nullptr, nullptr);
  // 4) logits = qk^T*scale + bias, safe-masked -> attn region
  gemm_kernel<1><<<dim3(6, 6, 16), 256, 0, stream>>>(qb, 256, kb, 256, attn, 384,
      nullptr, nullptr, 0, 384, 384, 64, biasO, pm, vld);
  // 5) softmax + mask + renorm (in place)
  softmax_kernel<<<1536, 256, 0, stream>>>(attn, pm);
  // 6) PV
  gemm_kernel<2><<<dim3(1, 6, 16), 256, 0, stream>>>(attn, 384, vb, 256, ao, 256,
      nullptr, nullptr, 0, 384, 64, 384, nullptr, nullptr, nullptr);
  // 7) Wo + bo + residual(x) -> x1
  gemm_kernel<0><<<dim3(4, 24), 256, 0, stream>>>(ao, 256, Wo, 256, x1, 256,
      bo, x, 256, 1536, 256, 256, nullptr, nullptr, nullptr);
  // 8) ln2 -> xn (reuse)
  ln_kernel<<<384, 256, 0, stream>>>(x1, ln2g, ln2b, xn);
  // 9) FF1
  gemm_kernel<0><<<dim3(16, 24), 256, 0, stream>>>(xn, 256, ffW1, 256, hff, 1024,
      ffb1, nullptr, 0, 1536, 1024, 256, nullptr, nullptr, nullptr);
  // 10) gate: ag = a * gelu(g)
  gate_kernel<<<768, 256, 0, stream>>>(hff, ag);
  // 11) FF2 + ffb2 + residual(x1) -> x_out
  gemm_kernel<0><<<dim3(4, 24), 256, 0, stream>>>(ag, 512, ffW2, 512, xout, 256,
      ffb2, x1, 256, 1536, 256, 512, nullptr, nullptr, nullptr);
}

// Round 2
// 404.743 us; speedup vs baseline: 1.8359x; 1.8359x over previous
//
#include <hip/hip_runtime.h>
#include <hip/hip_bf16.h>
#include <float.h>

// Problem constants
#define Bz   4
#define Nn   384
#define Dd   256
#define Hh   4
#define DHh  64
#define HIDn 64
#define NSQ  (384*384)
#define NEG_MAX (-3.40282346638528859812e+38f)

__device__ __forceinline__ float gelu_f(float x){
  return 0.5f * x * (1.0f + erff(x * 0.70710678118654752f));
}
__device__ __forceinline__ float wsum(float v){
  #pragma unroll
  for (int o = 32; o > 0; o >>= 1) v += __shfl_xor(v, o, 64);
  return v;
}
__device__ __forceinline__ float wmax(float v){
  #pragma unroll
  for (int o = 32; o > 0; o >>= 1) v = fmaxf(v, __shfl_xor(v, o, 64));
  return v;
}
__device__ __forceinline__ float4 ld4(const float* p){ return *(const float4*)p; }

// ---------------------------------------------------------------------------
// degcell: dc[b*N+t][c] = E_deg[deg[b*N+t]][c] + E_cell[cell[b*N+t]][c]
// ---------------------------------------------------------------------------
__global__ __launch_bounds__(256) void degcell_kernel(
    const int* __restrict__ dgk, const int* __restrict__ ctk,
    const float* __restrict__ Edg, const float* __restrict__ Ec,
    float* __restrict__ dc)
{
  const int idx = blockIdx.x * 256 + threadIdx.x;      // over 1536*16 float4s
  if (idx >= Bz * Nn * 16) return;
  const int row = idx >> 4;
  const int q   = (idx & 15) << 2;
  const float4 a = ld4(Edg + (dgk[row] << 6) + q);
  const float4 b = ld4(Ec  + (ctk[row] << 6) + q);
  float4 o; o.x = a.x + b.x; o.y = a.y + b.y; o.z = a.z + b.z; o.w = a.w + b.w;
  *(float4*)(dc + ((size_t)row << 6) + q) = o;
}

// ---------------------------------------------------------------------------
// Fused pair kernel v2: cont-MLP -> +embeddings -> LN -> gelu -> bias head
// -> *pair_mask -> bias (B,H,N,N).  Lane = pair; pr[64] in REGISTERS
// (static indexing only).  W2 matvec is k-major: h1[k] is a scalar,
// W2^T row broadcast from LDS.  Embedding gathers are float4 (4 ch/chunk).
// ---------------------------------------------------------------------------
__global__ __launch_bounds__(256, 3) void pair_kernel(
    const float* __restrict__ cont, const int* __restrict__ pm,
    const int* __restrict__ dbk, const int* __restrict__ drk,
    const int* __restrict__ rpk, const int* __restrict__ hdk,
    const int* __restrict__ etk, const int* __restrict__ spk,
    const int* __restrict__ sck,
    const float* __restrict__ W1, const float* __restrict__ b1,
    const float* __restrict__ W2, const float* __restrict__ b2,
    const float* __restrict__ Ed, const float* __restrict__ Edi,
    const float* __restrict__ Er, const float* __restrict__ Eh,
    const float* __restrict__ Ee, const float* __restrict__ Esp,
    const float* __restrict__ Es,
    const float* __restrict__ lng, const float* __restrict__ lnb,
    const float* __restrict__ bW, const float* __restrict__ bb,
    const float* __restrict__ dc,
    float* __restrict__ biasOut)
{
  __shared__ float w2t[64 * 68];   // W2^T, row k holds W2[:,k]; pad 68
  const int tid  = threadIdx.x;
  const int lane = tid & 63;
  const int wid  = blockIdx.x * 4 + (tid >> 6);            // [0, 9216)
  const int rowU = __builtin_amdgcn_readfirstlane(wid / 6); // b*N+i (uniform)
  const int jb   = wid - rowU * 6;
  const int b    = rowU / Nn;
  const int i    = rowU - b * Nn;
  const int j    = jb * 64 + lane;
  const size_t p = (size_t)rowU * Nn + j;

  // stage W2^T into LDS (cooperative)
  for (int idx = tid; idx < 4096; idx += 256) {
    const int c = idx >> 6, k = idx & 63;
    w2t[k * 68 + c] = W2[idx];
  }

  // per-pair embedding indices (pre-scaled to row offsets)
  const int xdb = dbk[p] << 6, xdr = drk[p] << 6, xrp = rpk[p] << 6;
  const int xhd = hdk[p] << 6, xet = etk[p] << 6, xsp = spk[p] << 6;
  const int xsc = sck[p] << 6;
  const float* dcj = dc + ((size_t)(b * Nn + j) << 6);  // per-lane
  const float* dci = dc + ((size_t)rowU << 6);          // uniform -> s_load

  // pr[c] := b2 + all embedding contributions (float4 chunks, static idx)
  float pr[64];
  #pragma unroll
  for (int c0 = 0; c0 < 64; c0 += 4) {
    float4 a = ld4(b2 + c0);
    const float4 u = ld4(dci + c0);
    a.x += u.x; a.y += u.y; a.z += u.z; a.w += u.w;
    {
      const float4 t = ld4(dcj + c0);
      a.x += t.x; a.y += t.y; a.z += t.z; a.w += t.w;
    }
    const float4 t0 = ld4(Ed  + xdb + c0);
    const float4 t1 = ld4(Edi + xdr + c0);
    const float4 t2 = ld4(Er  + xrp + c0);
    const float4 t3 = ld4(Eh  + xhd + c0);
    const float4 t4 = ld4(Ee  + xet + c0);
    const float4 t5 = ld4(Esp + xsp + c0);
    const float4 t6 = ld4(Es  + xsc + c0);
    a.x += t0.x + t1.x + t2.x + t3.x + t4.x + t5.x + t6.x;
    a.y += t0.y + t1.y + t2.y + t3.y + t4.y + t5.y + t6.y;
    a.z += t0.z + t1.z + t2.z + t3.z + t4.z + t5.z + t6.z;
    a.w += t0.w + t1.w + t2.w + t3.w + t4.w + t5.w + t6.w;
    pr[c0 + 0] = a.x; pr[c0 + 1] = a.y; pr[c0 + 2] = a.z; pr[c0 + 3] = a.w;
  }

  // continuous features (6)
  const float* cp = cont + p * 6;
  const float f0 = cp[0], f1 = cp[1], f2 = cp[2];
  const float f3 = cp[3], f4 = cp[4], f5 = cp[5];

  __syncthreads();   // w2t ready

  // k-major matvec: pr[c] += W2[c][k] * gelu(W1[k]·f + b1[k])
  for (int k = 0; k < 64; ++k) {
    const float* w = W1 + k * 6;           // uniform -> scalar loads
    float s = b1[k];
    s = fmaf(w[0], f0, s); s = fmaf(w[1], f1, s); s = fmaf(w[2], f2, s);
    s = fmaf(w[3], f3, s); s = fmaf(w[4], f4, s); s = fmaf(w[5], f5, s);
    const float hk = gelu_f(s);
    const float* wr = w2t + k * 68;        // wave-uniform LDS row (broadcast)
    #pragma unroll
    for (int cc = 0; cc < 64; cc += 4) {
      const float4 w4 = ld4(wr + cc);
      pr[cc + 0] = fmaf(w4.x, hk, pr[cc + 0]);
      pr[cc + 1] = fmaf(w4.y, hk, pr[cc + 1]);
      pr[cc + 2] = fmaf(w4.z, hk, pr[cc + 2]);
      pr[cc + 3] = fmaf(w4.w, hk, pr[cc + 3]);
    }
  }

  // layer-norm stats (in-lane)
  float sum = 0.f, sq = 0.f;
  #pragma unroll
  for (int c = 0; c < 64; ++c) { sum += pr[c]; sq = fmaf(pr[c], pr[c], sq); }
  const float mean = sum * (1.f / 64.f);
  const float var  = sq * (1.f / 64.f) - mean * mean;
  const float inv  = rsqrtf(var + 1e-5f);

  // gelu(LN) -> 4-head dot
  float bh0 = 0.f, bh1 = 0.f, bh2 = 0.f, bh3 = 0.f;
  #pragma unroll
  for (int c = 0; c < 64; ++c) {
    const float g = gelu_f((pr[c] - mean) * inv * lng[c] + lnb[c]);
    bh0 = fmaf(bW[      c], g, bh0);
    bh1 = fmaf(bW[ 64 + c], g, bh1);
    bh2 = fmaf(bW[128 + c], g, bh2);
    bh3 = fmaf(bW[192 + c], g, bh3);
  }
  const float mk = pm[p] ? 1.f : 0.f;
  const size_t base = (size_t)b * (Hh * NSQ) + (size_t)i * Nn + j;
  biasOut[base + 0 * (size_t)NSQ] = (bh0 + bb[0]) * mk;
  biasOut[base + 1 * (size_t)NSQ] = (bh1 + bb[1]) * mk;
  biasOut[base + 2 * (size_t)NSQ] = (bh2 + bb[2]) * mk;
  biasOut[base + 3 * (size_t)NSQ] = (bh3 + bb[3]) * mk;
}

// ---------------------------------------------------------------------------
// LayerNorm over last dim (256). One wave per row, 4 rows per block.
// ---------------------------------------------------------------------------
__global__ __launch_bounds__(256) void ln_kernel(
    const float* __restrict__ x, const float* __restrict__ g,
    const float* __restrict__ bta, float* __restrict__ o)
{
  const int row  = blockIdx.x * 4 + (threadIdx.x >> 6);
  const int lane = threadIdx.x & 63;
  const float4 v = *(const float4*)(x + (size_t)row * Dd + lane * 4);
  float s = v.x + v.y + v.z + v.w;
  s = wsum(s);
  const float m = s * (1.f / 256.f);
  const float dx = v.x - m, dy = v.y - m, dz = v.z - m, dw = v.w - m;
  float q = dx*dx + dy*dy + dz*dz + dw*dw;
  q = wsum(q);
  const float inv = rsqrtf(q * (1.f / 256.f) + 1e-5f);
  const int d = lane * 4;
  const float4 gg = *(const float4*)(g + d);
  const float4 bb = *(const float4*)(bta + d);
  float4 out;
  out.x = dx * inv * gg.x + bb.x;
  out.y = dy * inv * gg.y + bb.y;
  out.z = dz * inv * gg.z + bb.z;
  out.w = dw * inv * gg.w + bb.w;
  *(float4*)(o + (size_t)row * Dd + d) = out;
}

// ---------------------------------------------------------------------------
// Tiled fp32 GEMM, 64x64 tile, TK=16, 4x4 microtile.
// MODE 0: C = A @ B^T (+bias)(+res)          grid (Nc/64, M/64)
// MODE 1: QK^T*scale + biasT, safe-mask      grid (6, 6, B*H)
// MODE 2: C = A @ B  (PV, B natural KxNc)    grid (1, 6, B*H)
// ---------------------------------------------------------------------------
template<int MODE>
__global__ __launch_bounds__(256) void gemm_kernel(
    const float* __restrict__ A, int sA,
    const float* __restrict__ Bm, int sB,
    float* __restrict__ Cc, int sC,
    const float* __restrict__ bias,
    const float* __restrict__ res, int sR,
    int M, int Nc, int K,
    const float* __restrict__ biasT, const int* __restrict__ pmask,
    const int* __restrict__ valid)
{
  __shared__ float As[16][68];
  __shared__ float Bs[16][68];
  const int tid = threadIdx.x;
  const int tm = tid & 15, tn = tid >> 4;
  const int m0 = blockIdx.y * 64, n0 = blockIdx.x * 64;

  const float* Ab = A; const float* Bb = Bm; float* Cb = Cc;
  const float* biasTb = biasT; const int* pmb = pmask; const int* vlb = valid;
  if (MODE != 0) {
    const int bz = blockIdx.z;
    const int b = bz >> 2, h = bz & 3;
    if (MODE == 1) {
      Ab = A  + (size_t)b * Nn * Dd + h * DHh;
      Bb = Bm + (size_t)b * Nn * Dd + h * DHh;
      Cb = Cc + (size_t)bz * NSQ;
      biasTb = biasT + (size_t)bz * NSQ;
      pmb = pmask + (size_t)b * NSQ;
      vlb = valid + b * Nn;
    } else {
      Ab = A  + (size_t)bz * NSQ;
      Bb = Bm + (size_t)b * Nn * Dd + h * DHh;
      Cb = Cc + (size_t)b * Nn * Dd + h * DHh;
    }
  }

  float acc[4][4] = {};
  for (int k0 = 0; k0 < K; k0 += 16) {
    {
      const int r = tid >> 2, kc = (tid & 3) << 2;
      const float4 v4 = *(const float4*)(Ab + (size_t)(m0 + r) * sA + (k0 + kc));
      As[kc+0][r] = v4.x; As[kc+1][r] = v4.y; As[kc+2][r] = v4.z; As[kc+3][r] = v4.w;
    }
    if (MODE != 2) {
      const int r = tid >> 2, kc = (tid & 3) << 2;
      const float4 v4 = *(const float4*)(Bb + (size_t)(n0 + r) * sB + (k0 + kc));
      Bs[kc+0][r] = v4.x; Bs[kc+1][r] = v4.y; Bs[kc+2][r] = v4.z; Bs[kc+3][r] = v4.w;
    } else {
      const int kk = tid >> 4, nn2 = (tid & 15) << 2;
      *(float4*)&Bs[kk][nn2] = *(const float4*)(Bb + (size_t)(k0 + kk) * sB + (n0 + nn2));
    }
    __syncthreads();
    #pragma unroll
    for (int kk = 0; kk < 16; ++kk) {
      const float4 a4 = *(const float4*)&As[kk][tm << 2];
      const float4 b4 = *(const float4*)&Bs[kk][tn << 2];
      const float av[4] = {a4.x, a4.y, a4.z, a4.w};
      const float bv[4] = {b4.x, b4.y, b4.z, b4.w};
      #pragma unroll
      for (int r = 0; r < 4; ++r)
        #pragma unroll
        for (int s = 0; s < 4; ++s)
          acc[r][s] = fmaf(av[r], bv[s], acc[r][s]);
    }
    __syncthreads();
  }

  #pragma unroll
  for (int r = 0; r < 4; ++r) {
    const int m = m0 + (tm << 2) + r;
    #pragma unroll
    for (int s = 0; s < 4; ++s) {
      const int n = n0 + (tn << 2) + s;
      float v = acc[r][s];
      if (MODE == 0) {
        if (bias) v += bias[n];
        if (res)  v += res[(size_t)m * sR + n];
        Cb[(size_t)m * sC + n] = v;
      } else if (MODE == 1) {
        v = v * 0.125f + biasTb[(size_t)m * Nn + n];
        const bool safe = (pmb[(size_t)m * Nn + n] != 0) || (vlb[m] == 0 && m == n);
        Cb[(size_t)m * Nn + n] = safe ? v : NEG_MAX;
      } else {
        Cb[(size_t)m * sC + n] = v;
      }
    }
  }
}

// ---------------------------------------------------------------------------
// Softmax + pair_mask re-mask + renormalize, in place. Wave per row (384).
// ---------------------------------------------------------------------------
__global__ __launch_bounds__(256) void softmax_kernel(
    float* __restrict__ att, const int* __restrict__ pm)
{
  const int row  = blockIdx.x * 4 + (threadIdx.x >> 6);   // [0, B*H*N)
  const int lane = threadIdx.x & 63;
  const int i  = row % Nn;
  const int bh = row / Nn;
  const int b  = bh / Hh;
  float* ar = att + (size_t)row * Nn;
  const int* pmr = pm + (size_t)b * NSQ + (size_t)i * Nn;

  float v[6];
  float mx = NEG_MAX;
  #pragma unroll
  for (int t = 0; t < 6; ++t) { v[t] = ar[lane + t * 64]; mx = fmaxf(mx, v[t]); }
  mx = wmax(mx);
  float s = 0.f;
  #pragma unroll
  for (int t = 0; t < 6; ++t) { v[t] = expf(v[t] - mx); s += v[t]; }
  s = wsum(s);
  const float invs = 1.f / s;
  float s2 = 0.f;
  #pragma unroll
  for (int t = 0; t < 6; ++t) {
    const float pv = (float)pmr[lane + t * 64];
    v[t] = v[t] * invs * pv;
    s2 += v[t];
  }
  s2 = wsum(s2);
  const float r = 1.f / fmaxf(s2, 1e-6f);
  #pragma unroll
  for (int t = 0; t < 6; ++t) ar[lane + t * 64] = v[t] * r;
}

// ---------------------------------------------------------------------------
// ag = a * gelu(g): h (M,1024) -> ag (M,512)
// ---------------------------------------------------------------------------
__global__ __launch_bounds__(256) void gate_kernel(
    const float* __restrict__ hff, float* __restrict__ ag)
{
  const int idx = blockIdx.x * 256 + threadIdx.x;   // over 1536*512/4
  if (idx >= 1536 * 128) return;
  const int m  = idx / 128;
  const int dq = idx - m * 128;
  const float4 a = *(const float4*)(hff + (size_t)m * 1024 + dq * 4);
  const float4 g = *(const float4*)(hff + (size_t)m * 1024 + 512 + dq * 4);
  float4 o;
  o.x = a.x * gelu_f(g.x); o.y = a.y * gelu_f(g.y);
  o.z = a.z * gelu_f(g.z); o.w = a.w * gelu_f(g.w);
  *(float4*)(ag + (size_t)m * 512 + dq * 4) = o;
}

// ---------------------------------------------------------------------------
extern "C" void kernel_launch(void* const* d_in, const int* in_sizes, int n_in,
                              void* d_out, int out_size, void* d_ws, size_t ws_size,
                              hipStream_t stream) {
  const float* x    = (const float*)d_in[0];
  const int*   pm   = (const int*)  d_in[1];
  const int*   vld  = (const int*)  d_in[2];
  const float* cont = (const float*)d_in[3];
  const int* dbk = (const int*)d_in[4];
  const int* drk = (const int*)d_in[5];
  const int* rpk = (const int*)d_in[6];
  const int* hdk = (const int*)d_in[7];
  const int* etk = (const int*)d_in[8];
  const int* spk = (const int*)d_in[9];
  const int* sck = (const int*)d_in[10];
  const int* dgk = (const int*)d_in[11];
  const int* ctk = (const int*)d_in[12];
  const float* Wq  = (const float*)d_in[13];
  const float* Wk  = (const float*)d_in[14];
  const float* Wv  = (const float*)d_in[15];
  const float* Wo  = (const float*)d_in[16];
  const float* bo  = (const float*)d_in[17];
  const float* cmW1 = (const float*)d_in[18];
  const float* cmb1 = (const float*)d_in[19];
  const float* cmW2 = (const float*)d_in[20];
  const float* cmb2 = (const float*)d_in[21];
  const float* Ed  = (const float*)d_in[22];
  const float* Edi = (const float*)d_in[23];
  const float* Er  = (const float*)d_in[24];
  const float* Eh  = (const float*)d_in[25];
  const float* Ee  = (const float*)d_in[26];
  const float* Esp = (const float*)d_in[27];
  const float* Edg = (const float*)d_in[28];
  const float* Ec  = (const float*)d_in[29];
  const float* Es  = (const float*)d_in[30];
  const float* blng = (const float*)d_in[31];
  const float* blnb = (const float*)d_in[32];
  const float* bW   = (const float*)d_in[33];
  const float* bb_  = (const float*)d_in[34];
  const float* ln1g = (const float*)d_in[35];
  const float* ln1b = (const float*)d_in[36];
  const float* ln2g = (const float*)d_in[37];
  const float* ln2b = (const float*)d_in[38];
  const float* ffW1 = (const float*)d_in[39];
  const float* ffb1 = (const float*)d_in[40];
  const float* ffW2 = (const float*)d_in[41];
  const float* ffb2 = (const float*)d_in[42];

  float* out   = (float*)d_out;
  float* xout  = out;                       // 393216
  float* attn  = out + 393216;              // 2359296 (logits in place)
  float* biasO = out + 393216 + 2359296;    // 2359296

  float* ws  = (float*)d_ws;
  float* xn  = ws;                 // 393216  (ln1 out; reused for ln2 out)
  float* qb  = ws + 393216;        // 393216
  float* kb  = ws + 786432;        // 393216
  float* vb  = ws + 1179648;       // 393216
  float* ao  = ws + 1572864;       // 393216
  float* x1  = ws + 1966080;       // 393216
  float* hff = ws + 2359296;       // 1572864
  float* ag  = qb;                 // reuse q+k region (dead after QK)
  float* dc  = hff;                // 98304; dead before FF1 writes hff

  // 0) degcell merge (tiny)
  degcell_kernel<<<96, 256, 0, stream>>>(dgk, ctk, Edg, Ec, dc);
  // 1) pair bias
  pair_kernel<<<2304, 256, 0, stream>>>(cont, pm, dbk, drk, rpk, hdk, etk, spk,
      sck, cmW1, cmb1, cmW2, cmb2, Ed, Edi, Er, Eh, Ee, Esp, Es,
      blng, blnb, bW, bb_, dc, biasO);
  // 2) ln1
  ln_kernel<<<384, 256, 0, stream>>>(x, ln1g, ln1b, xn);
  // 3) q, k, v projections
  gemm_kernel<0><<<dim3(4, 24), 256, 0, stream>>>(xn, 256, Wq, 256, qb, 256,
      nullptr, nullptr, 0, 1536, 256, 256, nullptr, nullptr, nullptr);
  gemm_kernel<0><<<dim3(4, 24), 256, 0, stream>>>(xn, 256, Wk, 256, kb, 256,
      nullptr, nullptr, 0, 1536, 256, 256, nullptr, nullptr, nullptr);
  gemm_kernel<0><<<dim3(4, 24), 256, 0, stream>>>(xn, 256, Wv, 256, vb, 256,
      nullptr, nullptr, 0, 1536, 256, 256, nullptr, nullptr, nullptr);
  // 4) logits = qk^T*scale + bias, safe-masked -> attn region
  gemm_kernel<1><<<dim3(6, 6, 16), 256, 0, stream>>>(qb, 256, kb, 256, attn, 384,
      nullptr, nullptr, 0, 384, 384, 64, biasO, pm, vld);
  // 5) softmax + mask + renorm (in place)
  softmax_kernel<<<1536, 256, 0, stream>>>(attn, pm);
  // 6) PV
  gemm_kernel<2><<<dim3(1, 6, 16), 256, 0, stream>>>(attn, 384, vb, 256, ao, 256,
      nullptr, nullptr, 0, 384, 64, 384, nullptr, nullptr, nullptr);
  // 7) Wo + bo + residual(x) -> x1
  gemm_kernel<0><<<dim3(4, 24), 256, 0, stream>>>(ao, 256, Wo, 256, x1, 256,
      bo, x, 256, 1536, 256, 256, nullptr, nullptr, nullptr);
  // 8) ln2 -> xn (reuse)
  ln_kernel<<<384, 256, 0, stream>>>(x1, ln2g, ln2b, xn);
  // 9) FF1
  gemm_kernel<0><<<dim3(16, 24), 256, 0, stream>>>(xn, 256, ffW1, 256, hff, 1024,
      ffb1, nullptr, 0, 1536, 1024, 256, nullptr, nullptr, nullptr);
  // 10) gate: ag = a * gelu(g)
  gate_kernel<<<768, 256, 0, stream>>>(hff, ag);
  // 11) FF2 + ffb2 + residual(x1) -> x_out
  gemm_kernel<0><<<dim3(4, 24), 256, 0, stream>>>(ag, 512, ffW2, 512, xout, 256,
      ffb2, x1, 256, 1536, 256, 512, nullptr, nullptr, nullptr);
}